// Round 23
// baseline (365.882 us; speedup 1.0000x reference)
//
#include <hip/hip_runtime.h>
#include <hip/hip_bf16.h>

#define NB 4
#define SL 2048
#define EM 768
#define NHD 12
#define DHD 64
#define MLPD 3072
#define NHASH 4
#define NBS 48        // NB*NHD
#define NPOS 98304    // NBS*SL
#define MLROWS 8192   // NB*SL

typedef __attribute__((ext_vector_type(8))) short short8;
typedef __attribute__((ext_vector_type(8))) _Float16 f16x8;
typedef __attribute__((ext_vector_type(4))) float f32x4;

__device__ __forceinline__ unsigned short f2bf(float x){
  unsigned u = __float_as_uint(x);
  u += 0x7fffu + ((u>>16)&1u);
  return (unsigned short)(u>>16);
}
__device__ __forceinline__ float bf2f(unsigned short s){
  return __uint_as_float(((unsigned)s)<<16);
}
// 128B-row swizzle (8 slots of 16B): conflict-free for col-slice reads
__device__ __forceinline__ int sw128(int row, int colbyte){ return row*128 + (colbyte ^ ((row&7)<<4)); }
__device__ __forceinline__ int sw256(int row, int colbyte){ return row*256 + (colbyte ^ ((row&7)<<4)); }
// 64B-row swizzle (4 slots of 16B): slot ^= (row>>1)&3 -> 2-way (free) on frag reads
__device__ __forceinline__ int sw64(int row, int slot){ return row*64 + ((slot ^ ((row>>1)&3))<<4); }

// async global->LDS, 16B per lane; LDS dest = wave-uniform base + lane*16
__device__ __forceinline__ void gll16(const void* g, const void* l){
  __builtin_amdgcn_global_load_lds(
      (const __attribute__((address_space(1))) void*)(uintptr_t)g,
      (__attribute__((address_space(3))) void*)(unsigned int)(uintptr_t)l,
      16, 0, 0);
}

// ---------------- fused prep: float4 weight split/casts + hash weights + LN1 (one launch) ----------------
// blocks [0,6912): weights, 4 elems/thread via float4
// [6912,7040): whash rows (block 6912 also zero-inits scal)
// [7040,15232): LN1 rows
__global__ __launch_bounds__(256) void prep_all(const float* __restrict__ wqkv,
    const float* __restrict__ wout, const float* __restrict__ w1, const float* __restrict__ w2,
    const float* __restrict__ bqkv, const float* __restrict__ alpha,
    const float* __restrict__ x, const float* __restrict__ ln1g, const float* __restrict__ ln1b,
    _Float16* __restrict__ wq_h, _Float16* __restrict__ wq_l,
    unsigned short* __restrict__ wo_b, unsigned short* __restrict__ w1_b, unsigned short* __restrict__ w2_b,
    _Float16* __restrict__ wh_h, _Float16* __restrict__ wh_l, float* __restrict__ bias_h,
    _Float16* __restrict__ hh, _Float16* __restrict__ hl,
    unsigned* __restrict__ scal){
  int bid = blockIdx.x, tid = threadIdx.x;
  if (bid < 6912){
    int i = (bid*256 + tid)*4;        // 4 consecutive elements
    if (i < 1769472){
      float4 f = *(const float4*)(wqkv + i);
      float vv[4] = {f.x, f.y, f.z, f.w};
      _Float16 hi[4], lo[4];
      #pragma unroll
      for (int e=0;e<4;e++){
        float v = vv[e]*1024.0f;      // pre-scale keeps lo part out of fp16 denorms
        _Float16 h = (_Float16)v;
        hi[e] = h;
        lo[e] = (_Float16)((v - (float)h)*2048.0f);
      }
      *(uint2*)(wq_h + i) = *(uint2*)hi;
      *(uint2*)(wq_l + i) = *(uint2*)lo;
    } else {
      const float* src; unsigned short* dst; int j;
      if (i < 2359296){ j = i - 1769472; src = wout; dst = wo_b; }
      else if (i < 4718592){ j = i - 2359296; src = w1; dst = w1_b; }
      else { j = i - 4718592; src = w2; dst = w2_b; }
      float4 f = *(const float4*)(src + j);
      unsigned short o[4] = {f2bf(f.x), f2bf(f.y), f2bf(f.z), f2bf(f.w)};
      *(uint2*)(dst + j) = *(uint2*)o;
    }
    return;
  }
  if (bid < 7040){
    int row = bid - 6912;       // 0..127
    if (row == 0 && tid == 0){ scal[0] = 0u; scal[1] = 0u; }   // replaces hipMemsetAsync
    if (row >= 96){
      for (int c = tid; c < 768; c += 256){ wh_h[row*768+c] = (_Float16)0.f; wh_l[row*768+c] = (_Float16)0.f; }
      if (tid==0) bias_h[row] = 0.f;
      return;
    }
    int qk = row/48, hh2 = (row%48)>>2, r = row&3;
    float s = qk ? 1.0f : 0.125f;        // q pre-scaled by DH^-0.5
    int base = qk*768 + hh2*64;
    for (int c = tid; c < 768; c += 256){
      float acc = 0.f;
      #pragma unroll 8
      for (int d=0; d<64; d++)
        acc += wqkv[(size_t)(base+d)*768 + c] * alpha[d*4 + r];
      float v = acc*s*1024.0f;
      _Float16 h = (_Float16)v;
      wh_h[row*768+c] = h;
      wh_l[row*768+c] = (_Float16)((v - (float)h)*2048.0f);
    }
    if (tid==0){
      float b = 0.f;
      for (int d=0; d<64; d++) b += bqkv[base+d]*alpha[d*4+r];
      bias_h[row] = b*s;
    }
    return;
  }
  // ---- LN1 (bit-identical to prior rounds) ----
  int row = bid - 7040;
  __shared__ float sb[8];
  const float* xr = x + (size_t)row*EM;
  float v0 = xr[tid], v1 = xr[tid+256], v2 = xr[tid+512];
  float s = v0+v1+v2;
  #pragma unroll
  for (int off=32; off; off>>=1) s += __shfl_down(s, off);
  if ((tid&63)==0) sb[tid>>6] = s;
  __syncthreads();
  float mean = (sb[0]+sb[1]+sb[2]+sb[3]) * (1.0f/768.0f);
  float d0=v0-mean, d1=v1-mean, d2=v2-mean;
  float q_ = d0*d0 + d1*d1 + d2*d2;
  #pragma unroll
  for (int off=32; off; off>>=1) q_ += __shfl_down(q_, off);
  __syncthreads();
  if ((tid&63)==0) sb[tid>>6] = q_;
  __syncthreads();
  float var = (sb[0]+sb[1]+sb[2]+sb[3]) * (1.0f/768.0f);
  float rs = rsqrtf(var + 1e-6f);
  float dv[3] = {d0,d1,d2};
  #pragma unroll
  for (int e=0;e<3;e++){
    int cc = tid + e*256;
    float val = dv[e]*rs*ln1g[cc] + ln1b[cc];
    size_t oi = (size_t)row*EM + cc;
    _Float16 h = (_Float16)val;
    hh[oi] = h;
    hl[oi] = (_Float16)((val - (float)h)*2048.0f);
  }
}

// ---------------- LN2 (bf16 in -> bf16, vectorized) ----------------
__global__ __launch_bounds__(256) void ln2_kernel(const unsigned short* __restrict__ xb,
    const float* __restrict__ g, const float* __restrict__ bb, unsigned short* __restrict__ ob){
  int row = blockIdx.x; int tid = threadIdx.x;
  __shared__ float sb[8];
  float v[4] = {0.f,0.f,0.f,0.f};
  const bool act = tid < 192;
  if (act){
    uint2 u = *(const uint2*)(xb + (size_t)row*EM + tid*4);
    v[0]=bf2f((unsigned short)(u.x&0xFFFF)); v[1]=bf2f((unsigned short)(u.x>>16));
    v[2]=bf2f((unsigned short)(u.y&0xFFFF)); v[3]=bf2f((unsigned short)(u.y>>16));
  }
  float s = v[0]+v[1]+v[2]+v[3];
  #pragma unroll
  for (int off=32; off; off>>=1) s += __shfl_down(s, off);
  if ((tid&63)==0) sb[tid>>6] = s;
  __syncthreads();
  float mean = (sb[0]+sb[1]+sb[2]+sb[3]) * (1.0f/768.0f);
  float d[4], q_ = 0.f;
  #pragma unroll
  for (int e=0;e<4;e++){ d[e] = act ? v[e]-mean : 0.f; q_ += d[e]*d[e]; }
  #pragma unroll
  for (int off=32; off; off>>=1) q_ += __shfl_down(q_, off);
  __syncthreads();
  if ((tid&63)==0) sb[tid>>6] = q_;
  __syncthreads();
  float var = (sb[0]+sb[1]+sb[2]+sb[3]) * (1.0f/768.0f);
  float rs = rsqrtf(var + 1e-6f);
  if (act){
    unsigned short o[4];
    #pragma unroll
    for (int e=0;e<4;e++){
      int cc = tid*4+e;
      o[e] = f2bf(d[e]*rs*g[cc] + bb[cc]);
    }
    uint2 u; u.x = (unsigned)o[0] | ((unsigned)o[1]<<16); u.y = (unsigned)o[2] | ((unsigned)o[3]<<16);
    *(uint2*)(ob + (size_t)row*EM + tid*4) = u;
  }
}

// ---------------- QK + hash GEMM (8-wave blocks, BK=32 dbuf prefetch, Al reg-staged) ----------------
// 512 threads, grid 64x13. y in [0,12): qk path fp16x2 | y==12: hash path fp16x2.
// LDS 49.4KB (Ah/Bh/Bl staged; Al in NAMED register dbuf, manual 2-step loop -> no
// runtime-indexed register arrays, rule#20-safe) -> 3 blocks/CU = 24 waves/CU.
__global__ __launch_bounds__(512) void qk_gemm(const _Float16* __restrict__ Ah, const _Float16* __restrict__ Al,
    const _Float16* __restrict__ Wh, const _Float16* __restrict__ Wl,
    const _Float16* __restrict__ wh_h, const _Float16* __restrict__ wh_l,
    const float* __restrict__ bias, const float* __restrict__ bias_h,
    unsigned short* __restrict__ qb16, unsigned short* __restrict__ kb16,
    float* __restrict__ qsq, float* __restrict__ ksq, unsigned* __restrict__ scal,
    float* __restrict__ hqp, float* __restrict__ hkp){
  __shared__ __align__(16) char smem[49152];    // dbuf x (Ah 8K | Bh 8K | Bl 8K)
  __shared__ float smx_s[8];
  const int tid=threadIdx.x, l=tid&63, w=tid>>6, wm=w>>1, wn=w&1;   // w 0..7
  const int by = blockIdx.y;
  const int m0 = blockIdx.x*128;
  const int srow = l>>2;                          // source row within 16-row wave chunk
  const int scol = ((l&3)^((l>>3)&3))<<3;         // pre-swizzled source col (elements)
  // K-step-invariant fragment LDS offsets (sw64); wave-tile 32 rows x 64 cols
  int oa[2], ob_[4];
  #pragma unroll
  for (int i=0;i<2;i++) oa[i]  = sw64(wm*32 + i*16 + (l&15), l>>4);
  #pragma unroll
  for (int j=0;j<4;j++) ob_[j] = sw64(wn*64 + j*16 + (l&15), l>>4);
  const bool ishash = (by == 12);
  const int n0 = ishash ? 0 : by*128;
  const _Float16* Bh0 = ishash ? wh_h : (Wh + (size_t)n0*EM);
  const _Float16* Bl0 = ishash ? wh_l : (Wl + (size_t)n0*EM);
  const _Float16* pAh = Ah  + (size_t)(m0 + w*16 + srow)*EM + scol;
  const _Float16* pBh = Bh0 + (size_t)(w*16 + srow)*EM + scol;
  const _Float16* pBl = Bl0 + (size_t)(w*16 + srow)*EM + scol;
  // direct per-thread A-lo fragment base: row m0 + wm*32 + (l&15) (+16 for i=1), col (l>>4)*8
  const _Float16* pAlg = Al + (size_t)(m0 + wm*32 + (l&15))*EM + ((l>>4)<<3);
  f32x4 a1[2][4] = {}; f32x4 a2[2][4] = {};
  f16x8 alA0, alA1, alB0, alB1;                  // named register dbuf (no arrays)
  auto stage = [&](int buf, int k0){
    char* b = smem + buf*24576 + w*1024;
    gll16(pAh + k0, b);
    gll16(pBh + k0, b +  8192);
    gll16(pBl + k0, b + 16384);
  };
#define QK_LDAL(V0, V1, K0) { V0 = *(const f16x8*)(pAlg + (K0)); V1 = *(const f16x8*)(pAlg + (size_t)16*EM + (K0)); }
#define QK_COMP(S0, A0, A1) { \
    const char* s0_ = (S0); \
    f16x8 ah0 = *(const f16x8*)(s0_ + oa[0]); \
    f16x8 ah1 = *(const f16x8*)(s0_ + oa[1]); \
    _Pragma("unroll") \
    for (int j=0;j<4;j++){ \
      f16x8 bh = *(const f16x8*)(s0_ +  8192 + ob_[j]); \
      f16x8 bl = *(const f16x8*)(s0_ + 16384 + ob_[j]); \
      a1[0][j] = __builtin_amdgcn_mfma_f32_16x16x32_f16(ah0, bh, a1[0][j],0,0,0); \
      a2[0][j] = __builtin_amdgcn_mfma_f32_16x16x32_f16(ah0, bl, a2[0][j],0,0,0); \
      a2[0][j] = __builtin_amdgcn_mfma_f32_16x16x32_f16(A0,  bh, a2[0][j],0,0,0); \
      a1[1][j] = __builtin_amdgcn_mfma_f32_16x16x32_f16(ah1, bh, a1[1][j],0,0,0); \
      a2[1][j] = __builtin_amdgcn_mfma_f32_16x16x32_f16(ah1, bl, a2[1][j],0,0,0); \
      a2[1][j] = __builtin_amdgcn_mfma_f32_16x16x32_f16(A1,  bh, a2[1][j],0,0,0); \
    } }
  QK_LDAL(alA0, alA1, 0);
  stage(0, 0);
  __syncthreads();
  for (int tt=0; tt<12; tt++){
    int t0 = tt*2;                               // even step: buf0 + alA
    if (t0 < 23){ stage(1, (t0+1)*32); QK_LDAL(alB0, alB1, (t0+1)*32); }
    QK_COMP(smem, alA0, alA1);
    __syncthreads();
    int t1 = t0 + 1;                             // odd step: buf1 + alB
    if (t1 < 23){ stage(0, (t1+1)*32); QK_LDAL(alA0, alA1, (t1+1)*32); }
    QK_COMP(smem + 24576, alB0, alB1);
    __syncthreads();
  }
#undef QK_LDAL
#undef QK_COMP
  if (ishash){
    // epilogue: scatter hash projections (cols: qk*48 + head*4 + r)
    #pragma unroll
    for (int i=0;i<2;i++)
    #pragma unroll
    for (int rr=0;rr<4;rr++){
      int gm = m0 + wm*32 + i*16 + (l>>4)*4 + rr;
      int b = gm>>11, ll = gm&2047;
      #pragma unroll
      for (int j=0;j<4;j++){
        int col = wn*64 + j*16 + (l&15);
        if (col < 96){
          float v = (a1[i][j][rr] + a2[i][j][rr]*4.8828125e-4f)*9.765625e-4f + bias_h[col];
          int qk = col/48, hh = (col%48)>>2, r = col&3;
          size_t pos = ((size_t)(b*NHD+hh))*SL + ll;
          (qk ? hkp : hqp)[(size_t)r*NPOS + pos] = v;
        }
      }
    }
  } else {
    // epilogue: bf16 q/k + squared-norm reduction (LDS reduce + one atomic/block)
    const bool isq = (by < 6);
    const float so = isq ? 0.125f : 1.0f;  // q pre-scaled by DH^-0.5
    unsigned short* ob16 = isq ? qb16 : kb16;
    float* sqout = isq ? qsq : ksq;
    const int gn0 = n0 + wn*64;
    const int hh = (isq ? gn0 : gn0-768)>>6;
    float mx = 0.f;
    #pragma unroll
    for (int i=0;i<2;i++)
    #pragma unroll
    for (int rr=0;rr<4;rr++){
      int gm = m0 + wm*32 + i*16 + (l>>4)*4 + rr;
      int b = gm>>11, ll = gm&2047;
      size_t pos = ((size_t)(b*NHD+hh))*SL + ll;
      float vv[4]; float sq_p = 0.f;
      #pragma unroll
      for (int j=0;j<4;j++){
        int gn = gn0 + j*16 + (l&15);
        float v = (a1[i][j][rr] + a2[i][j][rr]*4.8828125e-4f)*9.765625e-4f + bias[gn];
        v *= so;
        vv[j] = v;
        sq_p += v*v;
      }
      #pragma unroll
      for (int j=0;j<4;j++)
        ob16[pos*DHD + j*16 + (l&15)] = f2bf(vv[j]);
      #pragma unroll
      for (int off2=1; off2<16; off2<<=1) sq_p += __shfl_xor(sq_p, off2);
      mx = fmaxf(mx, sq_p);
      if ((l&15)==0) sqout[pos] = sq_p;
    }
    mx = fmaxf(mx, __shfl_xor(mx, 16));
    mx = fmaxf(mx, __shfl_xor(mx, 32));
    if (l==0) smx_s[w] = mx;
    __syncthreads();
    if (tid==0){
      float m2 = smx_s[0];
      #pragma unroll
      for (int q2=1;q2<8;q2++) m2 = fmaxf(m2, smx_s[q2]);
      atomicMax(scal + (isq?0:1), __float_as_uint(m2));  // positives: uint order == float order
    }
  }
}

// ---------------- V GEMM (8-wave blocks, BK=32 dbuf prefetch, 32.8KB LDS -> 4 blocks/CU) ----------------
// 512 threads, grid 64x6. fp16-hi only (bf16-class output).
__global__ __launch_bounds__(512) void v_gemm(const _Float16* __restrict__ Ah,
    const _Float16* __restrict__ Wh, const float* __restrict__ bias,
    unsigned short* __restrict__ vo){
  __shared__ __align__(16) char smem[32768];
  const int tid=threadIdx.x, l=tid&63, w=tid>>6, wm=w>>1, wn=w&1;   // w 0..7
  const int m0 = blockIdx.x*128;
  const int n0 = blockIdx.y*128;
  const int srow = l>>2, scol = ((l&3)^((l>>3)&3))<<3;
  int oa[2], ob_[4];
  #pragma unroll
  for (int i=0;i<2;i++) oa[i]  = sw64(wm*32 + i*16 + (l&15), l>>4);
  #pragma unroll
  for (int j=0;j<4;j++) ob_[j] = sw64(wn*64 + j*16 + (l&15), l>>4);
  const _Float16* pAh = Ah + (size_t)(m0 + w*16 + srow)*EM + scol;
  const _Float16* pBh = Wh + (size_t)(1536 + n0 + w*16 + srow)*EM + scol;
  f32x4 acc[2][4] = {};
  auto stage = [&](int buf, int k0){
    char* b = smem + buf*16384 + w*1024;
    gll16(pAh + k0, b);
    gll16(pBh + k0, b + 8192);
  };
  auto compute = [&](int buf){
    char* s0 = smem + buf*16384;
    f16x8 ah[2];
    #pragma unroll
    for (int i=0;i<2;i++) ah[i] = *(const f16x8*)(s0 + oa[i]);
    #pragma unroll
    for (int j=0;j<4;j++){
      f16x8 bh = *(const f16x8*)(s0 + 8192 + ob_[j]);
      #pragma unroll
      for (int i=0;i<2;i++)
        acc[i][j] = __builtin_amdgcn_mfma_f32_16x16x32_f16(ah[i], bh, acc[i][j],0,0,0);
    }
  };
  stage(0, 0);
  __syncthreads();
  #pragma unroll 2
  for (int t=0;t<24;t++){
    if (t<23) stage((t+1)&1, (t+1)*32);
    compute(t&1);
    __syncthreads();
  }
  #pragma unroll
  for (int i=0;i<2;i++)
  #pragma unroll
  for (int j=0;j<4;j++)
  #pragma unroll
  for (int rr=0;rr<4;rr++){
    int gm = m0 + wm*32 + i*16 + (l>>4)*4 + rr;
    int gn = n0 + wn*64 + j*16 + (l&15);
    float v = acc[i][j][rr]*9.765625e-4f + bias[1536+gn];
    int hh = gn>>6; int d = gn&63;
    int b = gm>>11; int ll = gm&2047;
    vo[(((size_t)(b*NHD+hh))*SL + ll)*DHD + d] = f2bf(v);
  }
}

// ---------------- bitonic argsort (u64-packed, stable), wave-exclusive phases ----------------
__global__ __launch_bounds__(1024) void sort_kernel(const float* __restrict__ hqp, const float* __restrict__ hkp,
    const float* __restrict__ qsq, const float* __restrict__ ksq, const unsigned* __restrict__ scal,
    const float* __restrict__ alpha, const float* __restrict__ beta,
    int* __restrict__ qpos, int* __restrict__ kpos){
  __shared__ unsigned long long sv[2048];
  int bid = blockIdx.x;
  bool isq = bid < 192;
  int row = isq ? bid : bid-192;    // = r*NBS + bs
  int r = row/NBS, bs = row%NBS;
  const float* hp  = (isq?hqp:hkp) + (size_t)r*NPOS + (size_t)bs*SL;
  const float* sqp = (isq?qsq:ksq) + (size_t)bs*SL;
  int* op = (isq?qpos:kpos) + (size_t)row*SL;
  float m_tot = __uint_as_float(scal[0]) + __uint_as_float(scal[1]);
  float ae = alpha[(isq?64:65)*4 + r];   // XBOX+ row: 64 for Q, 65 for K
  float be = beta[r];
  const int wv = threadIdx.x>>6, lane = threadIdx.x&63, seg = wv*128;
  #pragma unroll
  for (int s=0; s<2; s++){
    int i = seg + s*64 + lane;          // segment-local load (no barrier needed)
    float ext = sqrtf(fmaxf(m_tot - sqp[i], 0.f));
    float h = hp[i] + ext*ae + be;
    unsigned u = __float_as_uint(h);
    u ^= ((unsigned)((int)u>>31)) | 0x80000000u;   // monotone unsigned order
    sv[i] = ((unsigned long long)u<<32) | (unsigned)i;
  }
  for (int kk=2; kk<=SL; kk<<=1){
    for (int j=kk>>1; j>0; j>>=1){
      if (j >= 64 && kk >= 256) __syncthreads();   // only cross-wave steps + first local after them
      int t = threadIdx.x;
      int i1 = ((t & ~(j-1))<<1) | (t & (j-1));
      int i2 = i1 | j;
      bool up = (i1 & kk)==0;
      unsigned long long a = sv[i1], b = sv[i2];
      if ((a>b)==up){ sv[i1]=b; sv[i2]=a; }
    }
  }
  #pragma unroll
  for (int s=0; s<2; s++){
    int i = seg + s*64 + lane;          // segment-local store
    op[i] = (int)(unsigned)(sv[i] & 0xFFFFFFFFu);
  }
}

// ---------------- within-cluster attention (8 waves/block, uint4 gathers, XCD-clustered) ----------------
// 512 threads: wave w owns q-rows w*16..w*16+15 (halved wave state, 24 waves/CU at 3 blocks/CU).
__global__ __launch_bounds__(512) void attn_kernel(const unsigned short* __restrict__ qb,
    const unsigned short* __restrict__ kb, const unsigned short* __restrict__ v,
    const int* __restrict__ qpos, const int* __restrict__ kpos,
    unsigned short* __restrict__ oh, float* __restrict__ lseh){
  __shared__ __align__(16) char smem[50176];
  char* qs  = smem;               // [128][64] bf16 (sw128), later reused as P rows 0..63
  char* ks_ = smem + 16384;       // [128][64] bf16, later reused as P rows 64..127
  char* P   = smem;               // [128][128] bf16 (sw256 rows)
  char* vt  = smem + 32768;       // [64][128] bf16 V^T (sw256 rows)
  int* idxq = (int*)(smem + 49152);
  int* idxk = (int*)(smem + 49664);

  const int tid = threadIdx.x, l = tid&63, w = tid>>6;   // w 0..7
  // bijective XCD swizzle (3072%8==0): all 64 blocks sharing one bs land on one XCD
  const int lg = (((int)blockIdx.x)&7)*384 + (((int)blockIdx.x)>>3);
  const int c = lg&15, r = (lg>>4)&3, bs = lg>>6;
  const size_t rowbase = ((size_t)r*NBS + bs)*SL;
  if (tid < 128) idxq[tid] = qpos[rowbase + c*128 + tid];
  else if (tid < 256) idxk[tid-128] = kpos[rowbase + c*128 + (tid-128)];
  __syncthreads();

  const unsigned short* qbb = qb + (size_t)bs*SL*DHD;
  const unsigned short* kbb = kb + (size_t)bs*SL*DHD;
  const unsigned short* vb  = v  + (size_t)bs*SL*DHD;
  #pragma unroll
  for (int p=0;p<2;p++){
    int row = p*64 + (tid>>3); int ch = tid&7;   // 8 lanes x 16B cover one 128B row
    {
      int orig = idxq[row];
      uint4 u = *(const uint4*)(qbb + (size_t)orig*DHD + ch*8);
      *(uint4*)(qs + sw128(row, ch*16)) = u;
    }
    {
      int orig = idxk[row];
      uint4 u = *(const uint4*)(kbb + (size_t)orig*DHD + ch*8);
      *(uint4*)(ks_ + sw128(row, ch*16)) = u;
    }
    {
      int orig = idxk[row];
      uint4 vv = *(const uint4*)(vb + (size_t)orig*DHD + ch*8);
      unsigned short arr[8];
      *(uint4*)arr = vv;
      #pragma unroll
      for (int ii=0;ii<8;ii++){
        int d = ch*8+ii;
        *(unsigned short*)(vt + sw256(d, row*2)) = arr[ii];   // transpose on the fly
      }
    }
  }
  __syncthreads();

  // S = q_s @ k_s^T  (wave w: 16 q-rows x 128 k-cols)
  f32x4 sc[8] = {};
  __builtin_amdgcn_s_setprio(1);
  #pragma unroll
  for (int ks=0;ks<2;ks++){
    int cb = ks*64 + ((l>>4)<<4);
    short8 aq = *(const short8*)(qs + sw128(w*16 + (l&15), cb));
    #pragma unroll
    for (int nj=0;nj<8;nj++){
      short8 bk = *(const short8*)(ks_ + sw128(nj*16+(l&15), cb));
      sc[nj] = __builtin_amdgcn_mfma_f32_16x16x32_bf16(aq, bk, sc[nj],0,0,0);
    }
  }
  __builtin_amdgcn_s_setprio(0);
  __syncthreads();

  // row-wise softmax (16-lane groups hold a row)
  #pragma unroll
  for (int rr=0;rr<4;rr++){
    float mx = -3.0e38f;
    #pragma unroll
    for (int nj=0;nj<8;nj++) mx = fmaxf(mx, sc[nj][rr]);
    #pragma unroll
    for (int off=1; off<16; off<<=1) mx = fmaxf(mx, __shfl_xor(mx, off));
    float s = 0.f;
    #pragma unroll
    for (int nj=0;nj<8;nj++){ float p_ = expf(sc[nj][rr]-mx); sc[nj][rr]=p_; s += p_; }
    #pragma unroll
    for (int off=1; off<16; off<<=1) s += __shfl_xor(s, off);
    float inv = 1.0f/s;
    int row = w*16 + (l>>4)*4 + rr;
    #pragma unroll
    for (int nj=0;nj<8;nj++){
      int col = nj*16 + (l&15);
      *(unsigned short*)(P + sw256(row, col*2)) = f2bf(sc[nj][rr]*inv);
    }
    if ((l&15)==0){
      int orig = idxq[row];
      lseh[rowbase + orig] = mx + logf(s);
    }
  }
  __syncthreads();

  // O = P @ V
  f32x4 o[4] = {};
  __builtin_amdgcn_s_setprio(1);
  #pragma unroll
  for (int ks=0;ks<4;ks++){
    int cb = ks*64 + ((l>>4)<<4);
    short8 pa = *(const short8*)(P + sw256(w*16 + (l&15), cb));
    #pragma unroll
    for (int nd=0;nd<4;nd++){
      short8 bv = *(const short8*)(vt + sw256(nd*16+(l&15), cb));
      o[nd] = __builtin_amdgcn_mfma_f32_16x16x32_bf16(pa, bv, o[nd],0,0,0);
    }
  }
  __builtin_amdgcn_s_setprio(0);
  #pragma unroll
  for (int nd=0;nd<4;nd++)
  #pragma unroll
  for (int rr=0;rr<4;rr++){
    int row = w*16 + (l>>4)*4 + rr;
    int orig = idxq[row];
    oh[(rowbase + orig)*DHD + nd*16 + (l&15)] = f2bf(o[nd][rr]);
  }
}

// ---------------- merge hash rounds (vectorized: 4 elems/thread, uint2 IO) ----------------
__global__ __launch_bounds__(256) void merge_kernel(const unsigned short* __restrict__ oh,
    const float* __restrict__ lseh, unsigned short* __restrict__ attnb){
  int g = blockIdx.x*256 + threadIdx.x;        // 1.57M threads, 4 d each
  int pos = g>>4; int d0 = (g&15)<<2;
  int ll = pos & (SL-1); int bs = pos >> 11;
  float l0 = lseh[0*NPOS+pos], l1 = lseh[1*NPOS+pos], l2 = lseh[2*NPOS+pos], l3 = lseh[3*NPOS+pos];
  float mx = fmaxf(fmaxf(l0,l1),fmaxf(l2,l3));
  float w0 = expf(l0-mx), w1 = expf(l1-mx), w2 = expf(l2-mx), w3 = expf(l3-mx);
  float inv = 1.0f/(w0+w1+w2+w3);
  w0 *= inv; w1 *= inv; w2 *= inv; w3 *= inv;
  uint2 u0 = *(const uint2*)(oh + ((size_t)0*NPOS+pos)*DHD + d0);
  uint2 u1 = *(const uint2*)(oh + ((size_t)1*NPOS+pos)*DHD + d0);
  uint2 u2 = *(const uint2*)(oh + ((size_t)2*NPOS+pos)*DHD + d0);
  uint2 u3 = *(const uint2*)(oh + ((size_t)3*NPOS+pos)*DHD + d0);
  unsigned short a0[4], a1[4], a2[4], a3[4], ro[4];
  *(uint2*)a0 = u0; *(uint2*)a1 = u1; *(uint2*)a2 = u2; *(uint2*)a3 = u3;
  #pragma unroll
  for (int e=0;e<4;e++){
    float acc = w0*bf2f(a0[e]) + w1*bf2f(a1[e]) + w2*bf2f(a2[e]) + w3*bf2f(a3[e]);
    ro[e] = f2bf(acc);
  }
  int b = bs/NHD, hh = bs%NHD;
  *(uint2*)(attnb + ((size_t)(b*SL)+ll)*EM + hh*DHD + d0) = *(uint2*)ro;
}

// ---------------- generic bf16 NT GEMM (8-wave blocks, BK=64 dbuf prefetch) ----------------
// 512 threads: 8 waves, wave-tile 32 x BN/2. BK=64 halves barrier count vs BK=32.
// EPI 1: outb = bf16(gelu(acc + bias)).
// EPI 2: outb = bf16(acc + bias + res_f).
// EPI 3: outf = acc + bias + bf2f(res_b).
template<int EPI, int BN>
__global__ __launch_bounds__(512) void gemm_bf16(const unsigned short* __restrict__ A,
    const unsigned short* __restrict__ Bw, const float* __restrict__ bias,
    const float* __restrict__ res_f, const unsigned short* __restrict__ res_b,
    float* __restrict__ outf, unsigned short* __restrict__ outb,
    int M, int N, int K){
  constexpr int NJ = BN/32;          // frags per wave along N (BN=128 -> 4, BN=64 -> 2)
  constexpr int ABUF = 16384;        // 128 rows x 64 cols x 2B
  constexpr int BB = BN*128;         // B buffer bytes (BN rows x 64 cols x 2B)
  constexpr int BUF = ABUF + BB;
  __shared__ __align__(16) char smem[2*BUF];
  const int tid=threadIdx.x, l=tid&63, w=tid>>6, wm=w>>1, wn=w&1;   // w 0..7
  const int m0 = blockIdx.x*128, n0 = blockIdx.y*BN;
  const int srow = l>>3, scol = ((l&7)^srow)<<3;   // pre-swizzled source (sw128 involution)
  f32x4 acc[2][NJ] = {};
  const unsigned short* pA = A  + (size_t)(m0 + w*16 + srow)*K + scol;        // 2 chunks of 8 rows
  const unsigned short* pB = Bw + (size_t)(n0 + w*(BN==128?16:8) + srow)*K + scol;
  auto stage = [&](int buf, int k0){
    char* bA = smem + buf*BUF;
    char* bB = bA + ABUF;
    gll16(pA + k0,       bA + w*2048);
    gll16(pA + k0 + 8*K, bA + w*2048 + 1024);
    if constexpr (BN==128){
      gll16(pB + k0,       bB + w*2048);
      gll16(pB + k0 + 8*K, bB + w*2048 + 1024);
    } else {
      gll16(pB + k0, bB + w*1024);
    }
  };
  auto compute = [&](int buf){
    char* bA = smem + buf*BUF;
    char* bB = bA + ABUF;
    #pragma unroll
    for (int ks=0;ks<2;ks++){
      int cb = ks*64 + ((l>>4)<<4);
      short8 af[2], bfr[NJ];
      #pragma unroll
      for (int i=0;i<2;i++)
        af[i]  = *(const short8*)(bA + sw128(wm*32 + i*16 + (l&15), cb));
      #pragma unroll
      for (int j=0;j<NJ;j++)
        bfr[j] = *(const short8*)(bB + sw128(wn*(BN/2) + j*16 + (l&15), cb));
      #pragma unroll
      for (int i=0;i<2;i++)
      #pragma unroll
      for (int j=0;j<NJ;j++)
        acc[i][j] = __builtin_amdgcn_mfma_f32_16x16x32_bf16(af[i], bfr[j], acc[i][j],0,0,0);
    }
  };
  const int nt = K/64;
  stage(0, 0);
  __syncthreads();
  #pragma unroll 2
  for (int t=0;t<nt;t++){
    if (t<nt-1) stage((t+1)&1, (t+1)*64);
    compute(t&1);
    __syncthreads();
  }
  #pragma unroll
  for (int i=0;i<2;i++)
  #pragma unroll
  for (int j=0;j<NJ;j++)
  #pragma unroll
  for (int rr=0;rr<4;rr++){
    int gm = m0 + wm*32 + i*16 + (l>>4)*4 + rr;
    int gn = n0 + wn*(BN/2) + j*16 + (l&15);
    float v = acc[i][j][rr] + bias[gn];
    size_t oidx = (size_t)gm*N + gn;
    if (EPI==1){ float ge = 0.5f*v*(1.0f + erff(v*0.70710678118654752f)); outb[oidx] = f2bf(ge); }
    else if (EPI==2){ outb[oidx] = f2bf(v + res_f[oidx]); }
    else { outf[oidx] = v + bf2f(res_b[oidx]); }
  }
}

extern "C" void kernel_launch(void* const* d_in, const int* in_sizes, int n_in,
                              void* d_out, int out_size, void* d_ws, size_t ws_size,
                              hipStream_t stream){
  const float* x    = (const float*)d_in[0];
  const float* ln1g = (const float*)d_in[1];
  const float* ln1b = (const float*)d_in[2];
  const float* wqkv = (const float*)d_in[3];
  const float* bqkv = (const float*)d_in[4];
  const float* wout = (const float*)d_in[5];
  const float* bout = (const float*)d_in[6];
  const float* ln2g = (const float*)d_in[7];
  const float* ln2b = (const float*)d_in[8];
  const float* w1   = (const float*)d_in[9];
  const float* b1   = (const float*)d_in[10];
  const float* w2   = (const float*)d_in[11];
  const float* b2   = (const float*)d_in[12];
  const float* alpha= (const float*)d_in[13];
  const float* beta = (const float*)d_in[14];
  float* out = (float*)d_out;

  char* ws = (char*)d_ws;
  size_t off = 0;
  auto A = [&](size_t n)->char*{ char* p = ws+off; off += (n+255)&~(size_t)255; return p; };
  _Float16* h_hi = (_Float16*)A(12582912);
  _Float16* h_lo = (_Float16*)A(12582912);
  _Float16* wq_h = (_Float16*)A(3538944);
  _Float16* wq_l = (_Float16*)A(3538944);
  unsigned short* wo_b = (unsigned short*)A(1179648);
  unsigned short* w1_b = (unsigned short*)A(4718592);
  unsigned short* w2_b = (unsigned short*)A(4718592);
  _Float16* wh_h = (_Float16*)A(196608);
  _Float16* wh_l = (_Float16*)A(196608);
  float* bias_h  = (float*)A(512);
  unsigned short* qb16 = (unsigned short*)A(12582912);
  unsigned short* kb16 = (unsigned short*)A(12582912);
  unsigned short* vbuf = (unsigned short*)A(12582912);
  float* qsq = (float*)A(393216);
  float* ksq = (float*)A(393216);
  unsigned* scal = (unsigned*)A(256);
  float* hqp = (float*)A(1572864);
  float* hkp = (float*)A(1572864);
  int* qpos = (int*)A(1572864);
  int* kpos = (int*)A(1572864);
  unsigned short* oh = (unsigned short*)A(50331648);
  float* lseh = (float*)A(1572864);
  unsigned short* ub = (unsigned short*)A(50331648);
  // aliases (lifetime-disjoint)
  unsigned short* attnb = vbuf;                 // v dead after attn_kernel
  unsigned short* x2b = (unsigned short*)oh;    // oh dead after merge_kernel
  unsigned short* yb = (unsigned short*)h_hi;   // h dead after qk/v gemms

  prep_all<<<15232, 256, 0, stream>>>(wqkv, wout, w1, w2, bqkv, alpha, x, ln1g, ln1b,
                                      wq_h, wq_l, wo_b, w1_b, w2_b, wh_h, wh_l, bias_h, h_hi, h_lo, scal);
  qk_gemm<<<dim3(64,13), 512, 0, stream>>>(h_hi, h_lo, wq_h, wq_l, wh_h, wh_l, bqkv, bias_h,
                                           qb16, kb16, qsq, ksq, scal, hqp, hkp);
  v_gemm<<<dim3(64,6), 512, 0, stream>>>(h_hi, wq_h, bqkv, vbuf);
  sort_kernel<<<384, 1024, 0, stream>>>(hqp, hkp, qsq, ksq, scal, alpha, beta, qpos, kpos);
  attn_kernel<<<3072, 512, 0, stream>>>(qb16, kb16, vbuf, qpos, kpos, oh, lseh);
  merge_kernel<<<6144, 256, 0, stream>>>(oh, lseh, attnb);
  gemm_bf16<2,64><<<dim3(64,12),  512, 0, stream>>>(attnb, wo_b, bout, x, nullptr, nullptr, x2b, MLROWS, 768, 768);
  ln2_kernel<<<MLROWS, 256, 0, stream>>>(x2b, ln2g, ln2b, yb);
  gemm_bf16<1,128><<<dim3(64,24), 512, 0, stream>>>(yb, w1_b, b1, nullptr, nullptr, nullptr, ub, MLROWS, 3072, 768);
  gemm_bf16<3,64><<<dim3(64,12),  512, 0, stream>>>(ub, w2_b, b2, nullptr, x2b, out, nullptr, MLROWS, 768, 3072);
}

// Round 24
// 324.134 us; speedup vs baseline: 1.1288x; 1.1288x over previous
//
#include <hip/hip_runtime.h>
#include <hip/hip_bf16.h>

#define NB 4
#define SL 2048
#define EM 768
#define NHD 12
#define DHD 64
#define MLPD 3072
#define NHASH 4
#define NBS 48        // NB*NHD
#define NPOS 98304    // NBS*SL
#define MLROWS 8192   // NB*SL

typedef __attribute__((ext_vector_type(8))) short short8;
typedef __attribute__((ext_vector_type(8))) _Float16 f16x8;
typedef __attribute__((ext_vector_type(4))) float f32x4;

__device__ __forceinline__ unsigned short f2bf(float x){
  unsigned u = __float_as_uint(x);
  u += 0x7fffu + ((u>>16)&1u);
  return (unsigned short)(u>>16);
}
__device__ __forceinline__ float bf2f(unsigned short s){
  return __uint_as_float(((unsigned)s)<<16);
}
// 128B-row swizzle (8 slots of 16B): conflict-free for col-slice reads
__device__ __forceinline__ int sw128(int row, int colbyte){ return row*128 + (colbyte ^ ((row&7)<<4)); }
__device__ __forceinline__ int sw256(int row, int colbyte){ return row*256 + (colbyte ^ ((row&7)<<4)); }
// 64B-row swizzle (4 slots of 16B): slot ^= (row>>1)&3 -> 2-way (free) on frag reads
__device__ __forceinline__ int sw64(int row, int slot){ return row*64 + ((slot ^ ((row>>1)&3))<<4); }

// async global->LDS, 16B per lane; LDS dest = wave-uniform base + lane*16
__device__ __forceinline__ void gll16(const void* g, const void* l){
  __builtin_amdgcn_global_load_lds(
      (const __attribute__((address_space(1))) void*)(uintptr_t)g,
      (__attribute__((address_space(3))) void*)(unsigned int)(uintptr_t)l,
      16, 0, 0);
}

// ---------------- fused prep: float4 weight split/casts + hash weights + LN1 (one launch) ----------------
// blocks [0,6912): weights, 4 elems/thread via float4
// [6912,7040): whash rows (block 6912 also zero-inits scal)
// [7040,15232): LN1 rows
__global__ __launch_bounds__(256) void prep_all(const float* __restrict__ wqkv,
    const float* __restrict__ wout, const float* __restrict__ w1, const float* __restrict__ w2,
    const float* __restrict__ bqkv, const float* __restrict__ alpha,
    const float* __restrict__ x, const float* __restrict__ ln1g, const float* __restrict__ ln1b,
    _Float16* __restrict__ wq_h, _Float16* __restrict__ wq_l,
    unsigned short* __restrict__ wo_b, unsigned short* __restrict__ w1_b, unsigned short* __restrict__ w2_b,
    _Float16* __restrict__ wh_h, _Float16* __restrict__ wh_l, float* __restrict__ bias_h,
    _Float16* __restrict__ hh, _Float16* __restrict__ hl,
    unsigned* __restrict__ scal){
  int bid = blockIdx.x, tid = threadIdx.x;
  if (bid < 6912){
    int i = (bid*256 + tid)*4;        // 4 consecutive elements
    if (i < 1769472){
      float4 f = *(const float4*)(wqkv + i);
      float vv[4] = {f.x, f.y, f.z, f.w};
      _Float16 hi[4], lo[4];
      #pragma unroll
      for (int e=0;e<4;e++){
        float v = vv[e]*1024.0f;      // pre-scale keeps lo part out of fp16 denorms
        _Float16 h = (_Float16)v;
        hi[e] = h;
        lo[e] = (_Float16)((v - (float)h)*2048.0f);
      }
      *(uint2*)(wq_h + i) = *(uint2*)hi;
      *(uint2*)(wq_l + i) = *(uint2*)lo;
    } else {
      const float* src; unsigned short* dst; int j;
      if (i < 2359296){ j = i - 1769472; src = wout; dst = wo_b; }
      else if (i < 4718592){ j = i - 2359296; src = w1; dst = w1_b; }
      else { j = i - 4718592; src = w2; dst = w2_b; }
      float4 f = *(const float4*)(src + j);
      unsigned short o[4] = {f2bf(f.x), f2bf(f.y), f2bf(f.z), f2bf(f.w)};
      *(uint2*)(dst + j) = *(uint2*)o;
    }
    return;
  }
  if (bid < 7040){
    int row = bid - 6912;       // 0..127
    if (row == 0 && tid == 0){ scal[0] = 0u; scal[1] = 0u; }   // replaces hipMemsetAsync
    if (row >= 96){
      for (int c = tid; c < 768; c += 256){ wh_h[row*768+c] = (_Float16)0.f; wh_l[row*768+c] = (_Float16)0.f; }
      if (tid==0) bias_h[row] = 0.f;
      return;
    }
    int qk = row/48, hh2 = (row%48)>>2, r = row&3;
    float s = qk ? 1.0f : 0.125f;        // q pre-scaled by DH^-0.5
    int base = qk*768 + hh2*64;
    for (int c = tid; c < 768; c += 256){
      float acc = 0.f;
      #pragma unroll 8
      for (int d=0; d<64; d++)
        acc += wqkv[(size_t)(base+d)*768 + c] * alpha[d*4 + r];
      float v = acc*s*1024.0f;
      _Float16 h = (_Float16)v;
      wh_h[row*768+c] = h;
      wh_l[row*768+c] = (_Float16)((v - (float)h)*2048.0f);
    }
    if (tid==0){
      float b = 0.f;
      for (int d=0; d<64; d++) b += bqkv[base+d]*alpha[d*4+r];
      bias_h[row] = b*s;
    }
    return;
  }
  // ---- LN1 (bit-identical to prior rounds) ----
  int row = bid - 7040;
  __shared__ float sb[8];
  const float* xr = x + (size_t)row*EM;
  float v0 = xr[tid], v1 = xr[tid+256], v2 = xr[tid+512];
  float s = v0+v1+v2;
  #pragma unroll
  for (int off=32; off; off>>=1) s += __shfl_down(s, off);
  if ((tid&63)==0) sb[tid>>6] = s;
  __syncthreads();
  float mean = (sb[0]+sb[1]+sb[2]+sb[3]) * (1.0f/768.0f);
  float d0=v0-mean, d1=v1-mean, d2=v2-mean;
  float q_ = d0*d0 + d1*d1 + d2*d2;
  #pragma unroll
  for (int off=32; off; off>>=1) q_ += __shfl_down(q_, off);
  __syncthreads();
  if ((tid&63)==0) sb[tid>>6] = q_;
  __syncthreads();
  float var = (sb[0]+sb[1]+sb[2]+sb[3]) * (1.0f/768.0f);
  float rs = rsqrtf(var + 1e-6f);
  float dv[3] = {d0,d1,d2};
  #pragma unroll
  for (int e=0;e<3;e++){
    int cc = tid + e*256;
    float val = dv[e]*rs*ln1g[cc] + ln1b[cc];
    size_t oi = (size_t)row*EM + cc;
    _Float16 h = (_Float16)val;
    hh[oi] = h;
    hl[oi] = (_Float16)((val - (float)h)*2048.0f);
  }
}

// ---------------- LN2 (bf16 in -> bf16, vectorized) ----------------
__global__ __launch_bounds__(256) void ln2_kernel(const unsigned short* __restrict__ xb,
    const float* __restrict__ g, const float* __restrict__ bb, unsigned short* __restrict__ ob){
  int row = blockIdx.x; int tid = threadIdx.x;
  __shared__ float sb[8];
  float v[4] = {0.f,0.f,0.f,0.f};
  const bool act = tid < 192;
  if (act){
    uint2 u = *(const uint2*)(xb + (size_t)row*EM + tid*4);
    v[0]=bf2f((unsigned short)(u.x&0xFFFF)); v[1]=bf2f((unsigned short)(u.x>>16));
    v[2]=bf2f((unsigned short)(u.y&0xFFFF)); v[3]=bf2f((unsigned short)(u.y>>16));
  }
  float s = v[0]+v[1]+v[2]+v[3];
  #pragma unroll
  for (int off=32; off; off>>=1) s += __shfl_down(s, off);
  if ((tid&63)==0) sb[tid>>6] = s;
  __syncthreads();
  float mean = (sb[0]+sb[1]+sb[2]+sb[3]) * (1.0f/768.0f);
  float d[4], q_ = 0.f;
  #pragma unroll
  for (int e=0;e<4;e++){ d[e] = act ? v[e]-mean : 0.f; q_ += d[e]*d[e]; }
  #pragma unroll
  for (int off=32; off; off>>=1) q_ += __shfl_down(q_, off);
  __syncthreads();
  if ((tid&63)==0) sb[tid>>6] = q_;
  __syncthreads();
  float var = (sb[0]+sb[1]+sb[2]+sb[3]) * (1.0f/768.0f);
  float rs = rsqrtf(var + 1e-6f);
  if (act){
    unsigned short o[4];
    #pragma unroll
    for (int e=0;e<4;e++){
      int cc = tid*4+e;
      o[e] = f2bf(d[e]*rs*g[cc] + bb[cc]);
    }
    uint2 u; u.x = (unsigned)o[0] | ((unsigned)o[1]<<16); u.y = (unsigned)o[2] | ((unsigned)o[3]<<16);
    *(uint2*)(ob + (size_t)row*EM + tid*4) = u;
  }
}

// ---------------- QK + hash GEMM (8-wave blocks, BK=32 dbuf prefetch) ----------------
// 512 threads, grid 64x13. y in [0,12): qk path fp16x2 | y==12: hash path fp16x2
__global__ __launch_bounds__(512) void qk_gemm(const _Float16* __restrict__ Ah, const _Float16* __restrict__ Al,
    const _Float16* __restrict__ Wh, const _Float16* __restrict__ Wl,
    const _Float16* __restrict__ wh_h, const _Float16* __restrict__ wh_l,
    const float* __restrict__ bias, const float* __restrict__ bias_h,
    unsigned short* __restrict__ qb16, unsigned short* __restrict__ kb16,
    float* __restrict__ qsq, float* __restrict__ ksq, unsigned* __restrict__ scal,
    float* __restrict__ hqp, float* __restrict__ hkp){
  __shared__ __align__(16) char smem[65536];
  __shared__ float smx_s[8];
  const int tid=threadIdx.x, l=tid&63, w=tid>>6, wm=w>>1, wn=w&1;   // w 0..7
  const int by = blockIdx.y;
  const int m0 = blockIdx.x*128;
  const int srow = l>>2;                          // source row within 16-row wave chunk
  const int scol = ((l&3)^((l>>3)&3))<<3;         // pre-swizzled source col (elements)
  // K-step-invariant fragment LDS offsets (sw64); wave-tile 32 rows x 64 cols
  int oa[2], ob_[4];
  #pragma unroll
  for (int i=0;i<2;i++) oa[i]  = sw64(wm*32 + i*16 + (l&15), l>>4);
  #pragma unroll
  for (int j=0;j<4;j++) ob_[j] = sw64(wn*64 + j*16 + (l&15), l>>4);
  const bool ishash = (by == 12);
  const int n0 = ishash ? 0 : by*128;
  const _Float16* Bh0 = ishash ? wh_h : (Wh + (size_t)n0*EM);
  const _Float16* Bl0 = ishash ? wh_l : (Wl + (size_t)n0*EM);
  const _Float16* pAh = Ah  + (size_t)(m0 + w*16 + srow)*EM + scol;
  const _Float16* pAl = Al  + (size_t)(m0 + w*16 + srow)*EM + scol;
  const _Float16* pBh = Bh0 + (size_t)(w*16 + srow)*EM + scol;
  const _Float16* pBl = Bl0 + (size_t)(w*16 + srow)*EM + scol;
  f32x4 a1[2][4] = {}; f32x4 a2[2][4] = {};
  auto stage = [&](int buf, int k0){
    char* b = smem + buf*32768 + w*1024;
    gll16(pAh + k0, b);
    gll16(pAl + k0, b +  8192);
    gll16(pBh + k0, b + 16384);
    gll16(pBl + k0, b + 24576);
  };
  auto compute = [&](int buf){
    char* s0 = smem + buf*32768;
    f16x8 ah[2], al2[2];
    #pragma unroll
    for (int i=0;i<2;i++){
      ah[i]  = *(const f16x8*)(s0 + oa[i]);
      al2[i] = *(const f16x8*)(s0 + 8192 + oa[i]);
    }
    #pragma unroll
    for (int j=0;j<4;j++){
      f16x8 bh = *(const f16x8*)(s0 + 16384 + ob_[j]);
      f16x8 bl = *(const f16x8*)(s0 + 24576 + ob_[j]);
      #pragma unroll
      for (int i=0;i<2;i++){
        a1[i][j] = __builtin_amdgcn_mfma_f32_16x16x32_f16(ah[i],  bh, a1[i][j],0,0,0);
        a2[i][j] = __builtin_amdgcn_mfma_f32_16x16x32_f16(ah[i],  bl, a2[i][j],0,0,0);
        a2[i][j] = __builtin_amdgcn_mfma_f32_16x16x32_f16(al2[i], bh, a2[i][j],0,0,0);
      }
    }
  };
  stage(0, 0);
  __syncthreads();
  #pragma unroll 2
  for (int t=0;t<24;t++){
    if (t<23) stage((t+1)&1, (t+1)*32);   // prefetch overlaps compute
    compute(t&1);
    __syncthreads();                       // drains vmcnt + lgkmcnt
  }
  if (ishash){
    // epilogue: scatter hash projections (cols: qk*48 + head*4 + r)
    #pragma unroll
    for (int i=0;i<2;i++)
    #pragma unroll
    for (int rr=0;rr<4;rr++){
      int gm = m0 + wm*32 + i*16 + (l>>4)*4 + rr;
      int b = gm>>11, ll = gm&2047;
      #pragma unroll
      for (int j=0;j<4;j++){
        int col = wn*64 + j*16 + (l&15);
        if (col < 96){
          float v = (a1[i][j][rr] + a2[i][j][rr]*4.8828125e-4f)*9.765625e-4f + bias_h[col];
          int qk = col/48, hh = (col%48)>>2, r = col&3;
          size_t pos = ((size_t)(b*NHD+hh))*SL + ll;
          (qk ? hkp : hqp)[(size_t)r*NPOS + pos] = v;
        }
      }
    }
  } else {
    // epilogue: bf16 q/k + squared-norm reduction (LDS reduce + one atomic/block)
    const bool isq = (by < 6);
    const float so = isq ? 0.125f : 1.0f;  // q pre-scaled by DH^-0.5
    unsigned short* ob16 = isq ? qb16 : kb16;
    float* sqout = isq ? qsq : ksq;
    const int gn0 = n0 + wn*64;
    const int hh = (isq ? gn0 : gn0-768)>>6;
    float mx = 0.f;
    #pragma unroll
    for (int i=0;i<2;i++)
    #pragma unroll
    for (int rr=0;rr<4;rr++){
      int gm = m0 + wm*32 + i*16 + (l>>4)*4 + rr;
      int b = gm>>11, ll = gm&2047;
      size_t pos = ((size_t)(b*NHD+hh))*SL + ll;
      float vv[4]; float sq_p = 0.f;
      #pragma unroll
      for (int j=0;j<4;j++){
        int gn = gn0 + j*16 + (l&15);
        float v = (a1[i][j][rr] + a2[i][j][rr]*4.8828125e-4f)*9.765625e-4f + bias[gn];
        v *= so;
        vv[j] = v;
        sq_p += v*v;
      }
      #pragma unroll
      for (int j=0;j<4;j++)
        ob16[pos*DHD + j*16 + (l&15)] = f2bf(vv[j]);
      #pragma unroll
      for (int off2=1; off2<16; off2<<=1) sq_p += __shfl_xor(sq_p, off2);
      mx = fmaxf(mx, sq_p);
      if ((l&15)==0) sqout[pos] = sq_p;
    }
    mx = fmaxf(mx, __shfl_xor(mx, 16));
    mx = fmaxf(mx, __shfl_xor(mx, 32));
    if (l==0) smx_s[w] = mx;
    __syncthreads();
    if (tid==0){
      float m2 = smx_s[0];
      #pragma unroll
      for (int q2=1;q2<8;q2++) m2 = fmaxf(m2, smx_s[q2]);
      atomicMax(scal + (isq?0:1), __float_as_uint(m2));  // positives: uint order == float order
    }
  }
}

// ---------------- V GEMM (8-wave blocks, BK=32 dbuf prefetch, 32.8KB LDS -> 4 blocks/CU) ----------------
// 512 threads, grid 64x6. fp16-hi only (bf16-class output).
__global__ __launch_bounds__(512) void v_gemm(const _Float16* __restrict__ Ah,
    const _Float16* __restrict__ Wh, const float* __restrict__ bias,
    unsigned short* __restrict__ vo){
  __shared__ __align__(16) char smem[32768];
  const int tid=threadIdx.x, l=tid&63, w=tid>>6, wm=w>>1, wn=w&1;   // w 0..7
  const int m0 = blockIdx.x*128;
  const int n0 = blockIdx.y*128;
  const int srow = l>>2, scol = ((l&3)^((l>>3)&3))<<3;
  int oa[2], ob_[4];
  #pragma unroll
  for (int i=0;i<2;i++) oa[i]  = sw64(wm*32 + i*16 + (l&15), l>>4);
  #pragma unroll
  for (int j=0;j<4;j++) ob_[j] = sw64(wn*64 + j*16 + (l&15), l>>4);
  const _Float16* pAh = Ah + (size_t)(m0 + w*16 + srow)*EM + scol;
  const _Float16* pBh = Wh + (size_t)(1536 + n0 + w*16 + srow)*EM + scol;
  f32x4 acc[2][4] = {};
  auto stage = [&](int buf, int k0){
    char* b = smem + buf*16384 + w*1024;
    gll16(pAh + k0, b);
    gll16(pBh + k0, b + 8192);
  };
  auto compute = [&](int buf){
    char* s0 = smem + buf*16384;
    f16x8 ah[2];
    #pragma unroll
    for (int i=0;i<2;i++) ah[i] = *(const f16x8*)(s0 + oa[i]);
    #pragma unroll
    for (int j=0;j<4;j++){
      f16x8 bh = *(const f16x8*)(s0 + 8192 + ob_[j]);
      #pragma unroll
      for (int i=0;i<2;i++)
        acc[i][j] = __builtin_amdgcn_mfma_f32_16x16x32_f16(ah[i], bh, acc[i][j],0,0,0);
    }
  };
  stage(0, 0);
  __syncthreads();
  #pragma unroll 2
  for (int t=0;t<24;t++){
    if (t<23) stage((t+1)&1, (t+1)*32);
    compute(t&1);
    __syncthreads();
  }
  #pragma unroll
  for (int i=0;i<2;i++)
  #pragma unroll
  for (int j=0;j<4;j++)
  #pragma unroll
  for (int rr=0;rr<4;rr++){
    int gm = m0 + wm*32 + i*16 + (l>>4)*4 + rr;
    int gn = n0 + wn*64 + j*16 + (l&15);
    float v = acc[i][j][rr]*9.765625e-4f + bias[1536+gn];
    int hh = gn>>6; int d = gn&63;
    int b = gm>>11; int ll = gm&2047;
    vo[(((size_t)(b*NHD+hh))*SL + ll)*DHD + d] = f2bf(v);
  }
}

// ---------------- bitonic argsort (u64-packed, stable), wave-exclusive phases ----------------
__global__ __launch_bounds__(1024) void sort_kernel(const float* __restrict__ hqp, const float* __restrict__ hkp,
    const float* __restrict__ qsq, const float* __restrict__ ksq, const unsigned* __restrict__ scal,
    const float* __restrict__ alpha, const float* __restrict__ beta,
    int* __restrict__ qpos, int* __restrict__ kpos){
  __shared__ unsigned long long sv[2048];
  int bid = blockIdx.x;
  bool isq = bid < 192;
  int row = isq ? bid : bid-192;    // = r*NBS + bs
  int r = row/NBS, bs = row%NBS;
  const float* hp  = (isq?hqp:hkp) + (size_t)r*NPOS + (size_t)bs*SL;
  const float* sqp = (isq?qsq:ksq) + (size_t)bs*SL;
  int* op = (isq?qpos:kpos) + (size_t)row*SL;
  float m_tot = __uint_as_float(scal[0]) + __uint_as_float(scal[1]);
  float ae = alpha[(isq?64:65)*4 + r];   // XBOX+ row: 64 for Q, 65 for K
  float be = beta[r];
  const int wv = threadIdx.x>>6, lane = threadIdx.x&63, seg = wv*128;
  #pragma unroll
  for (int s=0; s<2; s++){
    int i = seg + s*64 + lane;          // segment-local load (no barrier needed)
    float ext = sqrtf(fmaxf(m_tot - sqp[i], 0.f));
    float h = hp[i] + ext*ae + be;
    unsigned u = __float_as_uint(h);
    u ^= ((unsigned)((int)u>>31)) | 0x80000000u;   // monotone unsigned order
    sv[i] = ((unsigned long long)u<<32) | (unsigned)i;
  }
  for (int kk=2; kk<=SL; kk<<=1){
    for (int j=kk>>1; j>0; j>>=1){
      if (j >= 64 && kk >= 256) __syncthreads();   // only cross-wave steps + first local after them
      int t = threadIdx.x;
      int i1 = ((t & ~(j-1))<<1) | (t & (j-1));
      int i2 = i1 | j;
      bool up = (i1 & kk)==0;
      unsigned long long a = sv[i1], b = sv[i2];
      if ((a>b)==up){ sv[i1]=b; sv[i2]=a; }
    }
  }
  #pragma unroll
  for (int s=0; s<2; s++){
    int i = seg + s*64 + lane;          // segment-local store
    op[i] = (int)(unsigned)(sv[i] & 0xFFFFFFFFu);
  }
}

// ---------------- within-cluster attention (8 waves/block, uint4 gathers, XCD-clustered) ----------------
// 512 threads: wave w owns q-rows w*16..w*16+15 (halved wave state, 24 waves/CU at 3 blocks/CU).
__global__ __launch_bounds__(512) void attn_kernel(const unsigned short* __restrict__ qb,
    const unsigned short* __restrict__ kb, const unsigned short* __restrict__ v,
    const int* __restrict__ qpos, const int* __restrict__ kpos,
    unsigned short* __restrict__ oh, float* __restrict__ lseh){
  __shared__ __align__(16) char smem[50176];
  char* qs  = smem;               // [128][64] bf16 (sw128), later reused as P rows 0..63
  char* ks_ = smem + 16384;       // [128][64] bf16, later reused as P rows 64..127
  char* P   = smem;               // [128][128] bf16 (sw256 rows)
  char* vt  = smem + 32768;       // [64][128] bf16 V^T (sw256 rows)
  int* idxq = (int*)(smem + 49152);
  int* idxk = (int*)(smem + 49664);

  const int tid = threadIdx.x, l = tid&63, w = tid>>6;   // w 0..7
  // bijective XCD swizzle (3072%8==0): all 64 blocks sharing one bs land on one XCD
  const int lg = (((int)blockIdx.x)&7)*384 + (((int)blockIdx.x)>>3);
  const int c = lg&15, r = (lg>>4)&3, bs = lg>>6;
  const size_t rowbase = ((size_t)r*NBS + bs)*SL;
  if (tid < 128) idxq[tid] = qpos[rowbase + c*128 + tid];
  else if (tid < 256) idxk[tid-128] = kpos[rowbase + c*128 + (tid-128)];
  __syncthreads();

  const unsigned short* qbb = qb + (size_t)bs*SL*DHD;
  const unsigned short* kbb = kb + (size_t)bs*SL*DHD;
  const unsigned short* vb  = v  + (size_t)bs*SL*DHD;
  #pragma unroll
  for (int p=0;p<2;p++){
    int row = p*64 + (tid>>3); int ch = tid&7;   // 8 lanes x 16B cover one 128B row
    {
      int orig = idxq[row];
      uint4 u = *(const uint4*)(qbb + (size_t)orig*DHD + ch*8);
      *(uint4*)(qs + sw128(row, ch*16)) = u;
    }
    {
      int orig = idxk[row];
      uint4 u = *(const uint4*)(kbb + (size_t)orig*DHD + ch*8);
      *(uint4*)(ks_ + sw128(row, ch*16)) = u;
    }
    {
      int orig = idxk[row];
      uint4 vv = *(const uint4*)(vb + (size_t)orig*DHD + ch*8);
      unsigned short arr[8];
      *(uint4*)arr = vv;
      #pragma unroll
      for (int ii=0;ii<8;ii++){
        int d = ch*8+ii;
        *(unsigned short*)(vt + sw256(d, row*2)) = arr[ii];   // transpose on the fly
      }
    }
  }
  __syncthreads();

  // S = q_s @ k_s^T  (wave w: 16 q-rows x 128 k-cols)
  f32x4 sc[8] = {};
  __builtin_amdgcn_s_setprio(1);
  #pragma unroll
  for (int ks=0;ks<2;ks++){
    int cb = ks*64 + ((l>>4)<<4);
    short8 aq = *(const short8*)(qs + sw128(w*16 + (l&15), cb));
    #pragma unroll
    for (int nj=0;nj<8;nj++){
      short8 bk = *(const short8*)(ks_ + sw128(nj*16+(l&15), cb));
      sc[nj] = __builtin_amdgcn_mfma_f32_16x16x32_bf16(aq, bk, sc[nj],0,0,0);
    }
  }
  __builtin_amdgcn_s_setprio(0);
  __syncthreads();

  // row-wise softmax (16-lane groups hold a row)
  #pragma unroll
  for (int rr=0;rr<4;rr++){
    float mx = -3.0e38f;
    #pragma unroll
    for (int nj=0;nj<8;nj++) mx = fmaxf(mx, sc[nj][rr]);
    #pragma unroll
    for (int off=1; off<16; off<<=1) mx = fmaxf(mx, __shfl_xor(mx, off));
    float s = 0.f;
    #pragma unroll
    for (int nj=0;nj<8;nj++){ float p_ = expf(sc[nj][rr]-mx); sc[nj][rr]=p_; s += p_; }
    #pragma unroll
    for (int off=1; off<16; off<<=1) s += __shfl_xor(s, off);
    float inv = 1.0f/s;
    int row = w*16 + (l>>4)*4 + rr;
    #pragma unroll
    for (int nj=0;nj<8;nj++){
      int col = nj*16 + (l&15);
      *(unsigned short*)(P + sw256(row, col*2)) = f2bf(sc[nj][rr]*inv);
    }
    if ((l&15)==0){
      int orig = idxq[row];
      lseh[rowbase + orig] = mx + logf(s);
    }
  }
  __syncthreads();

  // O = P @ V
  f32x4 o[4] = {};
  __builtin_amdgcn_s_setprio(1);
  #pragma unroll
  for (int ks=0;ks<4;ks++){
    int cb = ks*64 + ((l>>4)<<4);
    short8 pa = *(const short8*)(P + sw256(w*16 + (l&15), cb));
    #pragma unroll
    for (int nd=0;nd<4;nd++){
      short8 bv = *(const short8*)(vt + sw256(nd*16+(l&15), cb));
      o[nd] = __builtin_amdgcn_mfma_f32_16x16x32_bf16(pa, bv, o[nd],0,0,0);
    }
  }
  __builtin_amdgcn_s_setprio(0);
  #pragma unroll
  for (int nd=0;nd<4;nd++)
  #pragma unroll
  for (int rr=0;rr<4;rr++){
    int row = w*16 + (l>>4)*4 + rr;
    int orig = idxq[row];
    oh[(rowbase + orig)*DHD + nd*16 + (l&15)] = f2bf(o[nd][rr]);
  }
}

// ---------------- merge hash rounds (vectorized: 4 elems/thread, uint2 IO) ----------------
__global__ __launch_bounds__(256) void merge_kernel(const unsigned short* __restrict__ oh,
    const float* __restrict__ lseh, unsigned short* __restrict__ attnb){
  int g = blockIdx.x*256 + threadIdx.x;        // 1.57M threads, 4 d each
  int pos = g>>4; int d0 = (g&15)<<2;
  int ll = pos & (SL-1); int bs = pos >> 11;
  float l0 = lseh[0*NPOS+pos], l1 = lseh[1*NPOS+pos], l2 = lseh[2*NPOS+pos], l3 = lseh[3*NPOS+pos];
  float mx = fmaxf(fmaxf(l0,l1),fmaxf(l2,l3));
  float w0 = expf(l0-mx), w1 = expf(l1-mx), w2 = expf(l2-mx), w3 = expf(l3-mx);
  float inv = 1.0f/(w0+w1+w2+w3);
  w0 *= inv; w1 *= inv; w2 *= inv; w3 *= inv;
  uint2 u0 = *(const uint2*)(oh + ((size_t)0*NPOS+pos)*DHD + d0);
  uint2 u1 = *(const uint2*)(oh + ((size_t)1*NPOS+pos)*DHD + d0);
  uint2 u2 = *(const uint2*)(oh + ((size_t)2*NPOS+pos)*DHD + d0);
  uint2 u3 = *(const uint2*)(oh + ((size_t)3*NPOS+pos)*DHD + d0);
  unsigned short a0[4], a1[4], a2[4], a3[4], ro[4];
  *(uint2*)a0 = u0; *(uint2*)a1 = u1; *(uint2*)a2 = u2; *(uint2*)a3 = u3;
  #pragma unroll
  for (int e=0;e<4;e++){
    float acc = w0*bf2f(a0[e]) + w1*bf2f(a1[e]) + w2*bf2f(a2[e]) + w3*bf2f(a3[e]);
    ro[e] = f2bf(acc);
  }
  int b = bs/NHD, hh = bs%NHD;
  *(uint2*)(attnb + ((size_t)(b*SL)+ll)*EM + hh*DHD + d0) = *(uint2*)ro;
}

// ---------------- generic bf16 NT GEMM (8-wave blocks, BK=64 dbuf prefetch) ----------------
// 512 threads: 8 waves, wave-tile 32 x BN/2. BK=64 halves barrier count vs BK=32.
// EPI 1: outb = bf16(gelu(acc + bias)).
// EPI 2: outb = bf16(acc + bias + res_f).
// EPI 3: outf = acc + bias + bf2f(res_b).
template<int EPI, int BN>
__global__ __launch_bounds__(512) void gemm_bf16(const unsigned short* __restrict__ A,
    const unsigned short* __restrict__ Bw, const float* __restrict__ bias,
    const float* __restrict__ res_f, const unsigned short* __restrict__ res_b,
    float* __restrict__ outf, unsigned short* __restrict__ outb,
    int M, int N, int K){
  constexpr int NJ = BN/32;          // frags per wave along N (BN=128 -> 4, BN=64 -> 2)
  constexpr int ABUF = 16384;        // 128 rows x 64 cols x 2B
  constexpr int BB = BN*128;         // B buffer bytes (BN rows x 64 cols x 2B)
  constexpr int BUF = ABUF + BB;
  __shared__ __align__(16) char smem[2*BUF];
  const int tid=threadIdx.x, l=tid&63, w=tid>>6, wm=w>>1, wn=w&1;   // w 0..7
  const int m0 = blockIdx.x*128, n0 = blockIdx.y*BN;
  const int srow = l>>3, scol = ((l&7)^srow)<<3;   // pre-swizzled source (sw128 involution)
  f32x4 acc[2][NJ] = {};
  const unsigned short* pA = A  + (size_t)(m0 + w*16 + srow)*K + scol;        // 2 chunks of 8 rows
  const unsigned short* pB = Bw + (size_t)(n0 + w*(BN==128?16:8) + srow)*K + scol;
  auto stage = [&](int buf, int k0){
    char* bA = smem + buf*BUF;
    char* bB = bA + ABUF;
    gll16(pA + k0,       bA + w*2048);
    gll16(pA + k0 + 8*K, bA + w*2048 + 1024);
    if constexpr (BN==128){
      gll16(pB + k0,       bB + w*2048);
      gll16(pB + k0 + 8*K, bB + w*2048 + 1024);
    } else {
      gll16(pB + k0, bB + w*1024);
    }
  };
  auto compute = [&](int buf){
    char* bA = smem + buf*BUF;
    char* bB = bA + ABUF;
    #pragma unroll
    for (int ks=0;ks<2;ks++){
      int cb = ks*64 + ((l>>4)<<4);
      short8 af[2], bfr[NJ];
      #pragma unroll
      for (int i=0;i<2;i++)
        af[i]  = *(const short8*)(bA + sw128(wm*32 + i*16 + (l&15), cb));
      #pragma unroll
      for (int j=0;j<NJ;j++)
        bfr[j] = *(const short8*)(bB + sw128(wn*(BN/2) + j*16 + (l&15), cb));
      #pragma unroll
      for (int i=0;i<2;i++)
      #pragma unroll
      for (int j=0;j<NJ;j++)
        acc[i][j] = __builtin_amdgcn_mfma_f32_16x16x32_bf16(af[i], bfr[j], acc[i][j],0,0,0);
    }
  };
  const int nt = K/64;
  stage(0, 0);
  __syncthreads();
  #pragma unroll 2
  for (int t=0;t<nt;t++){
    if (t<nt-1) stage((t+1)&1, (t+1)*64);
    compute(t&1);
    __syncthreads();
  }
  #pragma unroll
  for (int i=0;i<2;i++)
  #pragma unroll
  for (int j=0;j<NJ;j++)
  #pragma unroll
  for (int rr=0;rr<4;rr++){
    int gm = m0 + wm*32 + i*16 + (l>>4)*4 + rr;
    int gn = n0 + wn*(BN/2) + j*16 + (l&15);
    float v = acc[i][j][rr] + bias[gn];
    size_t oidx = (size_t)gm*N + gn;
    if (EPI==1){ float ge = 0.5f*v*(1.0f + erff(v*0.70710678118654752f)); outb[oidx] = f2bf(ge); }
    else if (EPI==2){ outb[oidx] = f2bf(v + res_f[oidx]); }
    else { outf[oidx] = v + bf2f(res_b[oidx]); }
  }
}

extern "C" void kernel_launch(void* const* d_in, const int* in_sizes, int n_in,
                              void* d_out, int out_size, void* d_ws, size_t ws_size,
                              hipStream_t stream){
  const float* x    = (const float*)d_in[0];
  const float* ln1g = (const float*)d_in[1];
  const float* ln1b = (const float*)d_in[2];
  const float* wqkv = (const float*)d_in[3];
  const float* bqkv = (const float*)d_in[4];
  const float* wout = (const float*)d_in[5];
  const float* bout = (const float*)d_in[6];
  const float* ln2g = (const float*)d_in[7];
  const float* ln2b = (const float*)d_in[8];
  const float* w1   = (const float*)d_in[9];
  const float* b1   = (const float*)d_in[10];
  const float* w2   = (const float*)d_in[11];
  const float* b2   = (const float*)d_in[12];
  const float* alpha= (const float*)d_in[13];
  const float* beta = (const float*)d_in[14];
  float* out = (float*)d_out;

  char* ws = (char*)d_ws;
  size_t off = 0;
  auto A = [&](size_t n)->char*{ char* p = ws+off; off += (n+255)&~(size_t)255; return p; };
  _Float16* h_hi = (_Float16*)A(12582912);
  _Float16* h_lo = (_Float16*)A(12582912);
  _Float16* wq_h = (_Float16*)A(3538944);
  _Float16* wq_l = (_Float16*)A(3538944);
  unsigned short* wo_b = (unsigned short*)A(1179648);
  unsigned short* w1_b = (unsigned short*)A(4718592);
  unsigned short* w2_b = (unsigned short*)A(4718592);
  _Float16* wh_h = (_Float16*)A(196608);
  _Float16* wh_l = (_Float16*)A(196608);
  float* bias_h  = (float*)A(512);
  unsigned short* qb16 = (unsigned short*)A(12582912);
  unsigned short* kb16 = (unsigned short*)A(12582912);
  unsigned short* vbuf = (unsigned short*)A(12582912);
  float* qsq = (float*)A(393216);
  float* ksq = (float*)A(393216);
  unsigned* scal = (unsigned*)A(256);
  float* hqp = (float*)A(1572864);
  float* hkp = (float*)A(1572864);
  int* qpos = (int*)A(1572864);
  int* kpos = (int*)A(1572864);
  unsigned short* oh = (unsigned short*)A(50331648);
  float* lseh = (float*)A(1572864);
  unsigned short* ub = (unsigned short*)A(50331648);
  // aliases (lifetime-disjoint)
  unsigned short* attnb = vbuf;                 // v dead after attn_kernel
  unsigned short* x2b = (unsigned short*)oh;    // oh dead after merge_kernel
  unsigned short* yb = (unsigned short*)h_hi;   // h dead after qk/v gemms

  prep_all<<<15232, 256, 0, stream>>>(wqkv, wout, w1, w2, bqkv, alpha, x, ln1g, ln1b,
                                      wq_h, wq_l, wo_b, w1_b, w2_b, wh_h, wh_l, bias_h, h_hi, h_lo, scal);
  qk_gemm<<<dim3(64,13), 512, 0, stream>>>(h_hi, h_lo, wq_h, wq_l, wh_h, wh_l, bqkv, bias_h,
                                           qb16, kb16, qsq, ksq, scal, hqp, hkp);
  v_gemm<<<dim3(64,6), 512, 0, stream>>>(h_hi, wq_h, bqkv, vbuf);
  sort_kernel<<<384, 1024, 0, stream>>>(hqp, hkp, qsq, ksq, scal, alpha, beta, qpos, kpos);
  attn_kernel<<<3072, 512, 0, stream>>>(qb16, kb16, vbuf, qpos, kpos, oh, lseh);
  merge_kernel<<<6144, 256, 0, stream>>>(oh, lseh, attnb);
  gemm_bf16<2,64><<<dim3(64,12),  512, 0, stream>>>(attnb, wo_b, bout, x, nullptr, nullptr, x2b, MLROWS, 768, 768);
  ln2_kernel<<<MLROWS, 256, 0, stream>>>(x2b, ln2g, ln2b, yb);
  gemm_bf16<1,128><<<dim3(64,24), 512, 0, stream>>>(yb, w1_b, b1, nullptr, nullptr, nullptr, ub, MLROWS, 3072, 768);
  gemm_bf16<3,64><<<dim3(64,12),  512, 0, stream>>>(ub, w2_b, b2, nullptr, x2b, out, nullptr, MLROWS, 768, 3072);
}